// Round 9
// baseline (938.895 us; speedup 1.0000x reference)
//
#include <hip/hip_runtime.h>

// RK4 Gray-Scott, register-pipelined y-march, packed-f32, 2-slot LDS protocol.
// Block = 512 threads = full 1024-wide row (2 cols/thread via f2, wrap &511).
// Vertical neighbors from per-thread shift-register windows; horizontal +-3
// via LDS. KEY CHANGE vs the 101us version: each stage's row is written to
// LDS from window position [2] (one step before the consumer needs it), not
// at production (3 steps before). Lifetime 1 step -> 2 slots/stage -> 64 KiB
// -> 2 blocks/CU -> block A's VALU phase overlaps block B's LDS phase.
// Slot algebra: write slot t&1, read slot (t+1)&1 (written at t-1); barrier(t)
// separates step t+1 reads from step t+2 overwrites. One barrier per step.
// RK sum reconstructed: out = u0 + (1/12)(4Y1+8Y2+4Y3-16u0+k4).

typedef float f2 __attribute__((ext_vector_type(2)));

#define HROWS 32
#define NT    512
#define STEPS (HROWS + 24)

#define W0 ((-980.0f / 1e-4f) / 180.0f)
#define W1 ((  270.0f / 1e-4f) / 180.0f)
#define W2 (( -27.0f / 1e-4f) / 180.0f)
#define W3 ((   2.0f / 1e-4f) / 180.0f)

__device__ __forceinline__ f2 sp(float s) { f2 r; r.x = s; r.y = s; return r; }
__device__ __forceinline__ f2 pfma(float s, f2 a, f2 c) {
    return __builtin_elementwise_fma(sp(s), a, c);
}

struct Hq { f2 m2, m1, p1, p2; };   // LDS row at f2 indices tid-2,tid-1,tid+1,tid+2

__device__ __forceinline__ Hq rdq(const f2* __restrict__ L,
                                  int xm2, int xm1, int xp1, int xp2) {
    Hq q;
    q.m2 = L[xm2]; q.m1 = L[xm1]; q.p1 = L[xp1]; q.p2 = L[xp2];
    return q;
}

// 13-pt Laplacian, packed over 2 cols. w = 7-row vertical window (center w[3]).
__device__ __forceinline__ void evalp(const f2* __restrict__ w, const Hq& q,
                                      f2& lap, f2& ctr)
{
    ctr = w[3];
    f2 vp = pfma(W1, w[2] + w[4], pfma(W2, w[1] + w[5], sp(W3) * (w[0] + w[6])));
    f2 m1 = __builtin_shufflevector(q.m1, ctr, 1, 2);   // {a-1, b-1}
    f2 p1 = __builtin_shufflevector(ctr, q.p1, 1, 2);   // {a+1, b+1}
    f2 m3 = __builtin_shufflevector(q.m2, q.m1, 1, 2);  // {a-3, b-3}
    f2 p3 = __builtin_shufflevector(q.p1, q.p2, 1, 2);  // {a+3, b+3}
    f2 hp = pfma(W1, m1 + p1, pfma(W2, q.m1 + q.p1, sp(W3) * (m3 + p3)));
    lap = pfma(W0, ctr, hp + vp);
}

#define SH6(A)  { A[5]=A[4]; A[4]=A[3]; A[3]=A[2]; A[2]=A[1]; A[1]=A[0]; }
#define SH7(A)  { A[6]=A[5]; A[5]=A[4]; A[4]=A[3]; A[3]=A[2]; A[2]=A[1]; A[1]=A[0]; }
#define SH10(A) { A[9]=A[8]; A[8]=A[7]; A[7]=A[6]; A[6]=A[5]; A[5]=A[4]; A[4]=A[3]; A[3]=A[2]; A[2]=A[1]; A[1]=A[0]; }

__global__ __launch_bounds__(NT, 4) void rcnn_rk4_march(
    const float* __restrict__ h,
    const float* __restrict__ pCA, const float* __restrict__ pCB,
    const float* __restrict__ pNA, const float* __restrict__ pNB,
    const float* __restrict__ pf,  const float* __restrict__ pk,
    float* __restrict__ out)
{
    __shared__ f2 Su[4][2][NT], Sv[4][2][NT];   // [stage][slot][col] = 64 KiB

    const int tid = threadIdx.x;
    const int Y0  = blockIdx.x * HROWS;
    const int b   = blockIdx.z;

    const float NA = pNA[0], NB = pNB[0];
    const float ff = pf[0];
    const float kpf = pk[0] + pf[0];
    const float mu_u = 4e-5f / (1.0f + expf(-pCA[0]));
    const float mu_v = 4e-5f / (1.0f + expf(-pCB[0]));

    const size_t baseU = (size_t)b * 2u * 1048576u;
    const size_t baseV = baseU + 1048576u;
    const float* hU = h + baseU + 2 * tid;
    const float* hV = h + baseV + 2 * tid;
    float* oU = out + baseU + 2 * tid;
    float* oV = out + baseV + 2 * tid;

    const int xm2 = (tid - 2) & 511;
    const int xm1 = (tid - 1) & 511;
    const int xp1 = (tid + 1) & 511;
    const int xp2 = (tid + 2) & 511;

    // shift windows (post-shift at step t, yL = Y0-12+t):
    f2 u0u[7], u0v[7];     // u0 rows yL-j
    f2 du[6],  dv[6];      // u0 rows yL-7-j
    f2 y1u[10], y1v[10];   // Y1 rows yL-3-j
    f2 y2u[7],  y2v[7];    // Y2 rows yL-6-j
    f2 y3u[7],  y3v[7];    // Y3 rows yL-9-j

    const f2 z = sp(0.0f);
    #pragma unroll
    for (int j = 0; j < 7; ++j) { u0u[j]=z; u0v[j]=z; y2u[j]=z; y2v[j]=z; y3u[j]=z; y3v[j]=z; }
    #pragma unroll
    for (int j = 0; j < 6; ++j) { du[j]=z; dv[j]=z; }
    #pragma unroll
    for (int j = 0; j < 10; ++j) { y1u[j]=z; y1v[j]=z; }

    // 1-deep prefetch of own columns, row Y0-12
    f2 pu, pv;
    {
        int yl = (Y0 - 12) & 1023;
        pu = *(const f2*)(hU + (size_t)yl * 1024);
        pv = *(const f2*)(hV + (size_t)yl * 1024);
    }

#define STEP(D1, D2, D3, D4, tt)                                              \
  {                                                                           \
    const int t_ = (tt);                                                      \
    const int WS = t_ & 1;          /* write slot */                          \
    const int RS = (t_ + 1) & 1;    /* read slot (written at t-1) */          \
    /* consume prefetch: u0 row yL */                                         \
    SH6(du); SH6(dv); du[0] = u0u[6]; dv[0] = u0v[6];                         \
    SH7(u0u); SH7(u0v); u0u[0] = pu; u0v[0] = pv;                             \
    /* u0 row yL-2 -> LDS (consumed next step as stage-1 center row) */       \
    Su[0][WS][tid] = u0u[2]; Sv[0][WS][tid] = u0v[2];                         \
    /* issue prefetch for row yL+1 */                                         \
    {                                                                         \
      int yn = (Y0 - 11 + t_) & 1023;                                         \
      pu = *(const f2*)(hU + (size_t)yn * 1024);                              \
      pv = *(const f2*)(hV + (size_t)yn * 1024);                              \
    }                                                                         \
    if (D1) { /* k1 on u0, row yL-3 */                                        \
      Hq q1u = rdq(&Su[0][RS][0], xm2, xm1, xp1, xp2);                        \
      Hq q1v = rdq(&Sv[0][RS][0], xm2, xm1, xp1, xp2);                        \
      f2 lU, cU, lV, cV;                                                      \
      evalp(u0u, q1u, lU, cU);                                                \
      evalp(u0v, q1v, lV, cV);                                                \
      f2 uv2 = cU * cV * cV;                                                  \
      f2 kU = pfma(mu_u, lU, pfma(NA, uv2, pfma(-ff, cU, sp(ff))));           \
      f2 kV = pfma(mu_v, lV, pfma(NB, uv2, sp(-kpf) * cV));                   \
      f2 nu = pfma(0.25f, kU, cU), nv = pfma(0.25f, kV, cV);                  \
      SH10(y1u); SH10(y1v); y1u[0] = nu; y1v[0] = nv;                         \
      Su[1][WS][tid] = y1u[2]; Sv[1][WS][tid] = y1v[2];                       \
    }                                                                         \
    if (D2) { /* k2 on Y1, row yL-6 */                                        \
      Hq q2u = rdq(&Su[1][RS][0], xm2, xm1, xp1, xp2);                        \
      Hq q2v = rdq(&Sv[1][RS][0], xm2, xm1, xp1, xp2);                        \
      f2 lU, cU, lV, cV;                                                      \
      evalp(y1u, q2u, lU, cU);                                                \
      evalp(y1v, q2v, lV, cV);                                                \
      f2 uv2 = cU * cV * cV;                                                  \
      f2 kU = pfma(mu_u, lU, pfma(NA, uv2, pfma(-ff, cU, sp(ff))));           \
      f2 kV = pfma(mu_v, lV, pfma(NB, uv2, sp(-kpf) * cV));                   \
      f2 nu = pfma(0.25f, kU, u0u[6]), nv = pfma(0.25f, kV, u0v[6]);          \
      SH7(y2u); SH7(y2v); y2u[0] = nu; y2v[0] = nv;                           \
      Su[2][WS][tid] = y2u[2]; Sv[2][WS][tid] = y2v[2];                       \
    }                                                                         \
    if (D3) { /* k3 on Y2, row yL-9 */                                        \
      Hq q3u = rdq(&Su[2][RS][0], xm2, xm1, xp1, xp2);                        \
      Hq q3v = rdq(&Sv[2][RS][0], xm2, xm1, xp1, xp2);                        \
      f2 lU, cU, lV, cV;                                                      \
      evalp(y2u, q3u, lU, cU);                                                \
      evalp(y2v, q3v, lV, cV);                                                \
      f2 uv2 = cU * cV * cV;                                                  \
      f2 kU = pfma(mu_u, lU, pfma(NA, uv2, pfma(-ff, cU, sp(ff))));           \
      f2 kV = pfma(mu_v, lV, pfma(NB, uv2, sp(-kpf) * cV));                   \
      f2 nu = pfma(0.5f, kU, du[2]), nv = pfma(0.5f, kV, dv[2]);              \
      SH7(y3u); SH7(y3v); y3u[0] = nu; y3v[0] = nv;                           \
      Su[3][WS][tid] = y3u[2]; Sv[3][WS][tid] = y3v[2];                       \
    }                                                                         \
    if (D4) { /* k4 on Y3, row yL-12 ; write output */                        \
      Hq q4u = rdq(&Su[3][RS][0], xm2, xm1, xp1, xp2);                        \
      Hq q4v = rdq(&Sv[3][RS][0], xm2, xm1, xp1, xp2);                        \
      f2 lU, cU4, lV, cV4;                                                    \
      evalp(y3u, q4u, lU, cU4);                                               \
      evalp(y3v, q4v, lV, cV4);                                               \
      f2 uv2 = cU4 * cV4 * cV4;                                               \
      f2 kU = pfma(mu_u, lU, pfma(NA, uv2, pfma(-ff, cU4, sp(ff))));          \
      f2 kV = pfma(mu_v, lV, pfma(NB, uv2, sp(-kpf) * cV4));                  \
      f2 aU = pfma(4.0f, y1u[9], kU);                                         \
      aU = pfma(8.0f, y2u[6], aU);                                            \
      aU = pfma(4.0f, cU4, aU);                                               \
      aU = pfma(-16.0f, du[5], aU);                                           \
      f2 aV = pfma(4.0f, y1v[9], kV);                                         \
      aV = pfma(8.0f, y2v[6], aV);                                            \
      aV = pfma(4.0f, cV4, aV);                                               \
      aV = pfma(-16.0f, dv[5], aV);                                           \
      f2 oUq = pfma(1.0f / 12.0f, aU, du[5]);                                 \
      f2 oVq = pfma(1.0f / 12.0f, aV, dv[5]);                                 \
      int yS = Y0 + t_ - 24;                                                  \
      *(f2*)(oU + (size_t)yS * 1024) = oUq;                                   \
      *(f2*)(oV + (size_t)yS * 1024) = oVq;                                   \
    }                                                                         \
    asm volatile("s_waitcnt lgkmcnt(0)" ::: "memory");                        \
    __builtin_amdgcn_s_barrier();                                             \
  }

    int t = 0;
    #pragma unroll 2
    for (; t < 6;  ++t) STEP(0, 0, 0, 0, t)
    #pragma unroll 2
    for (; t < 12; ++t) STEP(1, 0, 0, 0, t)
    #pragma unroll 2
    for (; t < 18; ++t) STEP(1, 1, 0, 0, t)
    #pragma unroll 2
    for (; t < 24; ++t) STEP(1, 1, 1, 0, t)
    #pragma unroll 4
    for (; t < STEPS; ++t) STEP(1, 1, 1, 1, t)
#undef STEP
}

extern "C" void kernel_launch(void* const* d_in, const int* in_sizes, int n_in,
                              void* d_out, int out_size, void* d_ws, size_t ws_size,
                              hipStream_t stream) {
    const float* h   = (const float*)d_in[0];
    const float* pCA = (const float*)d_in[1];
    const float* pCB = (const float*)d_in[2];
    const float* pNA = (const float*)d_in[3];
    const float* pNB = (const float*)d_in[4];
    const float* pf  = (const float*)d_in[5];
    const float* pk  = (const float*)d_in[6];
    float* outp = (float*)d_out;

    dim3 grid(1024 / HROWS, 1, 16);   // 32 strips x 16 batches = 512 blocks
    dim3 block(NT);
    rcnn_rk4_march<<<grid, block, 0, stream>>>(h, pCA, pCB, pNA, pNB, pf, pk, outp);
}

// Round 10
// 119.125 us; speedup vs baseline: 7.8816x; 7.8816x over previous
//
#include <hip/hip_runtime.h>

// RK4 Gray-Scott, register-pipelined y-march, packed-f32, 2-slot LDS protocol.
// Block = 512 threads = full 1024-wide row (2 cols/thread via f2, wrap &511).
// Vertical neighbors from per-thread shift-register windows; horizontal +-3
// via LDS. Each stage's row is written to LDS from window position [2] (one
// step before the consumer needs it) -> lifetime 1 step -> 2 slots/stage ->
// 64 KiB -> 2 blocks/CU co-resident: block A's VALU overlaps block B's LDS.
// NOTE: __launch_bounds__ 2nd arg behaves as min BLOCKS/CU (CUDA semantics)
// on this toolchain: (512,4) forced VGPR=64 -> 1.9GB scratch spill (round 9).
// (512,2) caps VGPR at 128, which rounds 5-8 compiled spill-free.
// Slot algebra: write slot t&1, read slot (t+1)&1 (written at t-1); barrier(t)
// separates step t+1 reads from step t+2 overwrites. One barrier per step.
// RK sum reconstructed: out = u0 + (1/12)(4Y1+8Y2+4Y3-16u0+k4).

typedef float f2 __attribute__((ext_vector_type(2)));

#define HROWS 32
#define NT    512
#define STEPS (HROWS + 24)

#define W0 ((-980.0f / 1e-4f) / 180.0f)
#define W1 ((  270.0f / 1e-4f) / 180.0f)
#define W2 (( -27.0f / 1e-4f) / 180.0f)
#define W3 ((   2.0f / 1e-4f) / 180.0f)

__device__ __forceinline__ f2 sp(float s) { f2 r; r.x = s; r.y = s; return r; }
__device__ __forceinline__ f2 pfma(float s, f2 a, f2 c) {
    return __builtin_elementwise_fma(sp(s), a, c);
}

struct Hq { f2 m2, m1, p1, p2; };   // LDS row at f2 indices tid-2,tid-1,tid+1,tid+2

__device__ __forceinline__ Hq rdq(const f2* __restrict__ L,
                                  int xm2, int xm1, int xp1, int xp2) {
    Hq q;
    q.m2 = L[xm2]; q.m1 = L[xm1]; q.p1 = L[xp1]; q.p2 = L[xp2];
    return q;
}

// 13-pt Laplacian, packed over 2 cols. w = 7-row vertical window (center w[3]).
__device__ __forceinline__ void evalp(const f2* __restrict__ w, const Hq& q,
                                      f2& lap, f2& ctr)
{
    ctr = w[3];
    f2 vp = pfma(W1, w[2] + w[4], pfma(W2, w[1] + w[5], sp(W3) * (w[0] + w[6])));
    f2 m1 = __builtin_shufflevector(q.m1, ctr, 1, 2);   // {a-1, b-1}
    f2 p1 = __builtin_shufflevector(ctr, q.p1, 1, 2);   // {a+1, b+1}
    f2 m3 = __builtin_shufflevector(q.m2, q.m1, 1, 2);  // {a-3, b-3}
    f2 p3 = __builtin_shufflevector(q.p1, q.p2, 1, 2);  // {a+3, b+3}
    f2 hp = pfma(W1, m1 + p1, pfma(W2, q.m1 + q.p1, sp(W3) * (m3 + p3)));
    lap = pfma(W0, ctr, hp + vp);
}

#define SH6(A)  { A[5]=A[4]; A[4]=A[3]; A[3]=A[2]; A[2]=A[1]; A[1]=A[0]; }
#define SH7(A)  { A[6]=A[5]; A[5]=A[4]; A[4]=A[3]; A[3]=A[2]; A[2]=A[1]; A[1]=A[0]; }
#define SH10(A) { A[9]=A[8]; A[8]=A[7]; A[7]=A[6]; A[6]=A[5]; A[5]=A[4]; A[4]=A[3]; A[3]=A[2]; A[2]=A[1]; A[1]=A[0]; }

__global__ __launch_bounds__(NT, 2) void rcnn_rk4_march(
    const float* __restrict__ h,
    const float* __restrict__ pCA, const float* __restrict__ pCB,
    const float* __restrict__ pNA, const float* __restrict__ pNB,
    const float* __restrict__ pf,  const float* __restrict__ pk,
    float* __restrict__ out)
{
    __shared__ f2 Su[4][2][NT], Sv[4][2][NT];   // [stage][slot][col] = 64 KiB

    const int tid = threadIdx.x;
    const int Y0  = blockIdx.x * HROWS;
    const int b   = blockIdx.z;

    const float NA = pNA[0], NB = pNB[0];
    const float ff = pf[0];
    const float kpf = pk[0] + pf[0];
    const float mu_u = 4e-5f / (1.0f + expf(-pCA[0]));
    const float mu_v = 4e-5f / (1.0f + expf(-pCB[0]));

    const size_t baseU = (size_t)b * 2u * 1048576u;
    const size_t baseV = baseU + 1048576u;
    const float* hU = h + baseU + 2 * tid;
    const float* hV = h + baseV + 2 * tid;
    float* oU = out + baseU + 2 * tid;
    float* oV = out + baseV + 2 * tid;

    const int xm2 = (tid - 2) & 511;
    const int xm1 = (tid - 1) & 511;
    const int xp1 = (tid + 1) & 511;
    const int xp2 = (tid + 2) & 511;

    // shift windows (post-shift at step t, yL = Y0-12+t):
    f2 u0u[7], u0v[7];     // u0 rows yL-j
    f2 du[6],  dv[6];      // u0 rows yL-7-j
    f2 y1u[10], y1v[10];   // Y1 rows yL-3-j
    f2 y2u[7],  y2v[7];    // Y2 rows yL-6-j
    f2 y3u[7],  y3v[7];    // Y3 rows yL-9-j

    const f2 z = sp(0.0f);
    #pragma unroll
    for (int j = 0; j < 7; ++j) { u0u[j]=z; u0v[j]=z; y2u[j]=z; y2v[j]=z; y3u[j]=z; y3v[j]=z; }
    #pragma unroll
    for (int j = 0; j < 6; ++j) { du[j]=z; dv[j]=z; }
    #pragma unroll
    for (int j = 0; j < 10; ++j) { y1u[j]=z; y1v[j]=z; }

    // 1-deep prefetch of own columns, row Y0-12
    f2 pu, pv;
    {
        int yl = (Y0 - 12) & 1023;
        pu = *(const f2*)(hU + (size_t)yl * 1024);
        pv = *(const f2*)(hV + (size_t)yl * 1024);
    }

#define STEP(D1, D2, D3, D4, tt)                                              \
  {                                                                           \
    const int t_ = (tt);                                                      \
    const int WS = t_ & 1;          /* write slot */                          \
    const int RS = (t_ + 1) & 1;    /* read slot (written at t-1) */          \
    /* consume prefetch: u0 row yL */                                         \
    SH6(du); SH6(dv); du[0] = u0u[6]; dv[0] = u0v[6];                         \
    SH7(u0u); SH7(u0v); u0u[0] = pu; u0v[0] = pv;                             \
    /* u0 row yL-2 -> LDS (consumed next step as stage-1 center row) */       \
    Su[0][WS][tid] = u0u[2]; Sv[0][WS][tid] = u0v[2];                         \
    /* issue prefetch for row yL+1 */                                         \
    {                                                                         \
      int yn = (Y0 - 11 + t_) & 1023;                                         \
      pu = *(const f2*)(hU + (size_t)yn * 1024);                              \
      pv = *(const f2*)(hV + (size_t)yn * 1024);                              \
    }                                                                         \
    if (D1) { /* k1 on u0, row yL-3 */                                        \
      Hq q1u = rdq(&Su[0][RS][0], xm2, xm1, xp1, xp2);                        \
      Hq q1v = rdq(&Sv[0][RS][0], xm2, xm1, xp1, xp2);                        \
      f2 lU, cU, lV, cV;                                                      \
      evalp(u0u, q1u, lU, cU);                                                \
      evalp(u0v, q1v, lV, cV);                                                \
      f2 uv2 = cU * cV * cV;                                                  \
      f2 kU = pfma(mu_u, lU, pfma(NA, uv2, pfma(-ff, cU, sp(ff))));           \
      f2 kV = pfma(mu_v, lV, pfma(NB, uv2, sp(-kpf) * cV));                   \
      f2 nu = pfma(0.25f, kU, cU), nv = pfma(0.25f, kV, cV);                  \
      SH10(y1u); SH10(y1v); y1u[0] = nu; y1v[0] = nv;                         \
      Su[1][WS][tid] = y1u[2]; Sv[1][WS][tid] = y1v[2];                       \
    }                                                                         \
    if (D2) { /* k2 on Y1, row yL-6 */                                        \
      Hq q2u = rdq(&Su[1][RS][0], xm2, xm1, xp1, xp2);                        \
      Hq q2v = rdq(&Sv[1][RS][0], xm2, xm1, xp1, xp2);                        \
      f2 lU, cU, lV, cV;                                                      \
      evalp(y1u, q2u, lU, cU);                                                \
      evalp(y1v, q2v, lV, cV);                                                \
      f2 uv2 = cU * cV * cV;                                                  \
      f2 kU = pfma(mu_u, lU, pfma(NA, uv2, pfma(-ff, cU, sp(ff))));           \
      f2 kV = pfma(mu_v, lV, pfma(NB, uv2, sp(-kpf) * cV));                   \
      f2 nu = pfma(0.25f, kU, u0u[6]), nv = pfma(0.25f, kV, u0v[6]);          \
      SH7(y2u); SH7(y2v); y2u[0] = nu; y2v[0] = nv;                           \
      Su[2][WS][tid] = y2u[2]; Sv[2][WS][tid] = y2v[2];                       \
    }                                                                         \
    if (D3) { /* k3 on Y2, row yL-9 */                                        \
      Hq q3u = rdq(&Su[2][RS][0], xm2, xm1, xp1, xp2);                        \
      Hq q3v = rdq(&Sv[2][RS][0], xm2, xm1, xp1, xp2);                        \
      f2 lU, cU, lV, cV;                                                      \
      evalp(y2u, q3u, lU, cU);                                                \
      evalp(y2v, q3v, lV, cV);                                                \
      f2 uv2 = cU * cV * cV;                                                  \
      f2 kU = pfma(mu_u, lU, pfma(NA, uv2, pfma(-ff, cU, sp(ff))));           \
      f2 kV = pfma(mu_v, lV, pfma(NB, uv2, sp(-kpf) * cV));                   \
      f2 nu = pfma(0.5f, kU, du[2]), nv = pfma(0.5f, kV, dv[2]);              \
      SH7(y3u); SH7(y3v); y3u[0] = nu; y3v[0] = nv;                           \
      Su[3][WS][tid] = y3u[2]; Sv[3][WS][tid] = y3v[2];                       \
    }                                                                         \
    if (D4) { /* k4 on Y3, row yL-12 ; write output */                        \
      Hq q4u = rdq(&Su[3][RS][0], xm2, xm1, xp1, xp2);                        \
      Hq q4v = rdq(&Sv[3][RS][0], xm2, xm1, xp1, xp2);                        \
      f2 lU, cU4, lV, cV4;                                                    \
      evalp(y3u, q4u, lU, cU4);                                               \
      evalp(y3v, q4v, lV, cV4);                                               \
      f2 uv2 = cU4 * cV4 * cV4;                                               \
      f2 kU = pfma(mu_u, lU, pfma(NA, uv2, pfma(-ff, cU4, sp(ff))));          \
      f2 kV = pfma(mu_v, lV, pfma(NB, uv2, sp(-kpf) * cV4));                  \
      f2 aU = pfma(4.0f, y1u[9], kU);                                         \
      aU = pfma(8.0f, y2u[6], aU);                                            \
      aU = pfma(4.0f, cU4, aU);                                               \
      aU = pfma(-16.0f, du[5], aU);                                           \
      f2 aV = pfma(4.0f, y1v[9], kV);                                         \
      aV = pfma(8.0f, y2v[6], aV);                                            \
      aV = pfma(4.0f, cV4, aV);                                               \
      aV = pfma(-16.0f, dv[5], aV);                                           \
      f2 oUq = pfma(1.0f / 12.0f, aU, du[5]);                                 \
      f2 oVq = pfma(1.0f / 12.0f, aV, dv[5]);                                 \
      int yS = Y0 + t_ - 24;                                                  \
      *(f2*)(oU + (size_t)yS * 1024) = oUq;                                   \
      *(f2*)(oV + (size_t)yS * 1024) = oVq;                                   \
    }                                                                         \
    asm volatile("s_waitcnt lgkmcnt(0)" ::: "memory");                        \
    __builtin_amdgcn_s_barrier();                                             \
  }

    int t = 0;
    #pragma unroll 2
    for (; t < 6;  ++t) STEP(0, 0, 0, 0, t)
    #pragma unroll 2
    for (; t < 12; ++t) STEP(1, 0, 0, 0, t)
    #pragma unroll 2
    for (; t < 18; ++t) STEP(1, 1, 0, 0, t)
    #pragma unroll 2
    for (; t < 24; ++t) STEP(1, 1, 1, 0, t)
    #pragma unroll 4
    for (; t < STEPS; ++t) STEP(1, 1, 1, 1, t)
#undef STEP
}

extern "C" void kernel_launch(void* const* d_in, const int* in_sizes, int n_in,
                              void* d_out, int out_size, void* d_ws, size_t ws_size,
                              hipStream_t stream) {
    const float* h   = (const float*)d_in[0];
    const float* pCA = (const float*)d_in[1];
    const float* pCB = (const float*)d_in[2];
    const float* pNA = (const float*)d_in[3];
    const float* pNB = (const float*)d_in[4];
    const float* pf  = (const float*)d_in[5];
    const float* pk  = (const float*)d_in[6];
    float* outp = (float*)d_out;

    dim3 grid(1024 / HROWS, 1, 16);   // 32 strips x 16 batches = 512 blocks
    dim3 block(NT);
    rcnn_rk4_march<<<grid, block, 0, stream>>>(h, pCA, pCB, pNA, pNB, pf, pk, outp);
}

// Round 11
// 99.417 us; speedup vs baseline: 9.4440x; 1.1982x over previous
//
#include <hip/hip_runtime.h>

// RK4 Gray-Scott, register-pipelined y-march, packed-f32, f4-packed LDS.
// Block = 512 threads = full 1024-wide row (2 cols/thread via f2, wrap &511).
// Vertical neighbors from per-thread shift-register windows; horizontal +-3
// via LDS rows packed as f4 = {u.a, u.b, v.a, v.b}: ONE ds_read_b128 serves
// both channels -> 20 LDS instrs/thread-step instead of 40 (the kernel is
// LDS-instruction-issue-bound at ~8cyc/op: round5 320 ops -> 2750cyc/step,
// round10 640 ops -> 5100cyc/step).
// 2-slot protocol: stage row written from window[2] (1 step before use);
// write slot t&1, read slot (t+1)&1; one lgkmcnt(0)+barrier per step.
// RK sum reconstructed: out = u0 + (1/12)(4Y1+8Y2+4Y3-16u0+k4).

typedef float f2 __attribute__((ext_vector_type(2)));
typedef float f4 __attribute__((ext_vector_type(4)));

#define HROWS 64
#define NT    512
#define STEPS (HROWS + 24)

#define W0 ((-980.0f / 1e-4f) / 180.0f)
#define W1 ((  270.0f / 1e-4f) / 180.0f)
#define W2 (( -27.0f / 1e-4f) / 180.0f)
#define W3 ((   2.0f / 1e-4f) / 180.0f)

__device__ __forceinline__ f2 sp(float s) { f2 r; r.x = s; r.y = s; return r; }
__device__ __forceinline__ f2 pfma(float s, f2 a, f2 c) {
    return __builtin_elementwise_fma(sp(s), a, c);
}
__device__ __forceinline__ f2 lo2(f4 a) { return __builtin_shufflevector(a, a, 0, 1); }
__device__ __forceinline__ f2 hi2(f4 a) { return __builtin_shufflevector(a, a, 2, 3); }
__device__ __forceinline__ f4 cat(f2 a, f2 b) { return __builtin_shufflevector(a, b, 0, 1, 2, 3); }

struct Hq  { f2 m2, m1, p1, p2; };  // one channel's neighbors
struct Hq4 { f4 m2, m1, p1, p2; };  // both channels packed

__device__ __forceinline__ Hq4 rdq4(const f4* __restrict__ L,
                                    int xm2, int xm1, int xp1, int xp2) {
    Hq4 q;
    q.m2 = L[xm2]; q.m1 = L[xm1]; q.p1 = L[xp1]; q.p2 = L[xp2];
    return q;
}

// 13-pt Laplacian, packed over 2 cols. w = 7-row vertical window (center w[3]).
__device__ __forceinline__ void evalp(const f2* __restrict__ w, const Hq& q,
                                      f2& lap, f2& ctr)
{
    ctr = w[3];
    f2 vp = pfma(W1, w[2] + w[4], pfma(W2, w[1] + w[5], sp(W3) * (w[0] + w[6])));
    f2 m1 = __builtin_shufflevector(q.m1, ctr, 1, 2);   // {a-1, b-1}
    f2 p1 = __builtin_shufflevector(ctr, q.p1, 1, 2);   // {a+1, b+1}
    f2 m3 = __builtin_shufflevector(q.m2, q.m1, 1, 2);  // {a-3, b-3}
    f2 p3 = __builtin_shufflevector(q.p1, q.p2, 1, 2);  // {a+3, b+3}
    f2 hp = pfma(W1, m1 + p1, pfma(W2, q.m1 + q.p1, sp(W3) * (m3 + p3)));
    lap = pfma(W0, ctr, hp + vp);
}

#define SH6(A)  { A[5]=A[4]; A[4]=A[3]; A[3]=A[2]; A[2]=A[1]; A[1]=A[0]; }
#define SH7(A)  { A[6]=A[5]; A[5]=A[4]; A[4]=A[3]; A[3]=A[2]; A[2]=A[1]; A[1]=A[0]; }
#define SH10(A) { A[9]=A[8]; A[8]=A[7]; A[7]=A[6]; A[6]=A[5]; A[5]=A[4]; A[4]=A[3]; A[3]=A[2]; A[2]=A[1]; A[1]=A[0]; }

__global__ __launch_bounds__(NT, 2) void rcnn_rk4_march(
    const float* __restrict__ h,
    const float* __restrict__ pCA, const float* __restrict__ pCB,
    const float* __restrict__ pNA, const float* __restrict__ pNB,
    const float* __restrict__ pf,  const float* __restrict__ pk,
    float* __restrict__ out)
{
    __shared__ f4 S[4][2][NT];   // [stage][slot][col] {u.a,u.b,v.a,v.b} = 64 KiB

    const int tid = threadIdx.x;
    const int Y0  = blockIdx.x * HROWS;
    const int b   = blockIdx.z;

    const float NA = pNA[0], NB = pNB[0];
    const float ff = pf[0];
    const float kpf = pk[0] + pf[0];
    const float mu_u = 4e-5f / (1.0f + expf(-pCA[0]));
    const float mu_v = 4e-5f / (1.0f + expf(-pCB[0]));

    const size_t baseU = (size_t)b * 2u * 1048576u;
    const size_t baseV = baseU + 1048576u;
    const float* hU = h + baseU + 2 * tid;
    const float* hV = h + baseV + 2 * tid;
    float* oU = out + baseU + 2 * tid;
    float* oV = out + baseV + 2 * tid;

    const int xm2 = (tid - 2) & 511;
    const int xm1 = (tid - 1) & 511;
    const int xp1 = (tid + 1) & 511;
    const int xp2 = (tid + 2) & 511;

    // shift windows (post-shift at step t, yL = Y0-12+t):
    f2 u0u[7], u0v[7];     // u0 rows yL-j
    f2 du[6],  dv[6];      // u0 rows yL-7-j
    f2 y1u[10], y1v[10];   // Y1 rows yL-3-j
    f2 y2u[7],  y2v[7];    // Y2 rows yL-6-j
    f2 y3u[7],  y3v[7];    // Y3 rows yL-9-j

    const f2 z = sp(0.0f);
    #pragma unroll
    for (int j = 0; j < 7; ++j) { u0u[j]=z; u0v[j]=z; y2u[j]=z; y2v[j]=z; y3u[j]=z; y3v[j]=z; }
    #pragma unroll
    for (int j = 0; j < 6; ++j) { du[j]=z; dv[j]=z; }
    #pragma unroll
    for (int j = 0; j < 10; ++j) { y1u[j]=z; y1v[j]=z; }

    // 1-deep prefetch of own columns, row Y0-12
    f2 pu, pv;
    {
        int yl = (Y0 - 12) & 1023;
        pu = *(const f2*)(hU + (size_t)yl * 1024);
        pv = *(const f2*)(hV + (size_t)yl * 1024);
    }

#define STEP(D1, D2, D3, D4, tt)                                              \
  {                                                                           \
    const int t_ = (tt);                                                      \
    const int WS = t_ & 1;          /* write slot */                          \
    const int RS = (t_ + 1) & 1;    /* read slot (written at t-1) */          \
    /* consume prefetch: u0 row yL */                                         \
    SH6(du); SH6(dv); du[0] = u0u[6]; dv[0] = u0v[6];                         \
    SH7(u0u); SH7(u0v); u0u[0] = pu; u0v[0] = pv;                             \
    /* u0 row yL-2 -> LDS (consumed next step as stage-1 center row) */       \
    S[0][WS][tid] = cat(u0u[2], u0v[2]);                                      \
    /* issue prefetch for row yL+1 */                                         \
    {                                                                         \
      int yn = (Y0 - 11 + t_) & 1023;                                         \
      pu = *(const f2*)(hU + (size_t)yn * 1024);                              \
      pv = *(const f2*)(hV + (size_t)yn * 1024);                              \
    }                                                                         \
    if (D1) { /* k1 on u0, row yL-3 */                                        \
      Hq4 q = rdq4(&S[0][RS][0], xm2, xm1, xp1, xp2);                         \
      Hq qu = { lo2(q.m2), lo2(q.m1), lo2(q.p1), lo2(q.p2) };                 \
      Hq qv = { hi2(q.m2), hi2(q.m1), hi2(q.p1), hi2(q.p2) };                 \
      f2 lU, cU, lV, cV;                                                      \
      evalp(u0u, qu, lU, cU);                                                 \
      evalp(u0v, qv, lV, cV);                                                 \
      f2 uv2 = cU * cV * cV;                                                  \
      f2 kU = pfma(mu_u, lU, pfma(NA, uv2, pfma(-ff, cU, sp(ff))));           \
      f2 kV = pfma(mu_v, lV, pfma(NB, uv2, sp(-kpf) * cV));                   \
      f2 nu = pfma(0.25f, kU, cU), nv = pfma(0.25f, kV, cV);                  \
      SH10(y1u); SH10(y1v); y1u[0] = nu; y1v[0] = nv;                         \
      S[1][WS][tid] = cat(y1u[2], y1v[2]);                                    \
    }                                                                         \
    if (D2) { /* k2 on Y1, row yL-6 */                                        \
      Hq4 q = rdq4(&S[1][RS][0], xm2, xm1, xp1, xp2);                         \
      Hq qu = { lo2(q.m2), lo2(q.m1), lo2(q.p1), lo2(q.p2) };                 \
      Hq qv = { hi2(q.m2), hi2(q.m1), hi2(q.p1), hi2(q.p2) };                 \
      f2 lU, cU, lV, cV;                                                      \
      evalp(y1u, qu, lU, cU);                                                 \
      evalp(y1v, qv, lV, cV);                                                 \
      f2 uv2 = cU * cV * cV;                                                  \
      f2 kU = pfma(mu_u, lU, pfma(NA, uv2, pfma(-ff, cU, sp(ff))));           \
      f2 kV = pfma(mu_v, lV, pfma(NB, uv2, sp(-kpf) * cV));                   \
      f2 nu = pfma(0.25f, kU, u0u[6]), nv = pfma(0.25f, kV, u0v[6]);          \
      SH7(y2u); SH7(y2v); y2u[0] = nu; y2v[0] = nv;                           \
      S[2][WS][tid] = cat(y2u[2], y2v[2]);                                    \
    }                                                                         \
    if (D3) { /* k3 on Y2, row yL-9 */                                        \
      Hq4 q = rdq4(&S[2][RS][0], xm2, xm1, xp1, xp2);                         \
      Hq qu = { lo2(q.m2), lo2(q.m1), lo2(q.p1), lo2(q.p2) };                 \
      Hq qv = { hi2(q.m2), hi2(q.m1), hi2(q.p1), hi2(q.p2) };                 \
      f2 lU, cU, lV, cV;                                                      \
      evalp(y2u, qu, lU, cU);                                                 \
      evalp(y2v, qv, lV, cV);                                                 \
      f2 uv2 = cU * cV * cV;                                                  \
      f2 kU = pfma(mu_u, lU, pfma(NA, uv2, pfma(-ff, cU, sp(ff))));           \
      f2 kV = pfma(mu_v, lV, pfma(NB, uv2, sp(-kpf) * cV));                   \
      f2 nu = pfma(0.5f, kU, du[2]), nv = pfma(0.5f, kV, dv[2]);              \
      SH7(y3u); SH7(y3v); y3u[0] = nu; y3v[0] = nv;                           \
      S[3][WS][tid] = cat(y3u[2], y3v[2]);                                    \
    }                                                                         \
    if (D4) { /* k4 on Y3, row yL-12 ; write output */                        \
      Hq4 q = rdq4(&S[3][RS][0], xm2, xm1, xp1, xp2);                         \
      Hq qu = { lo2(q.m2), lo2(q.m1), lo2(q.p1), lo2(q.p2) };                 \
      Hq qv = { hi2(q.m2), hi2(q.m1), hi2(q.p1), hi2(q.p2) };                 \
      f2 lU, cU4, lV, cV4;                                                    \
      evalp(y3u, qu, lU, cU4);                                                \
      evalp(y3v, qv, lV, cV4);                                                \
      f2 uv2 = cU4 * cV4 * cV4;                                               \
      f2 kU = pfma(mu_u, lU, pfma(NA, uv2, pfma(-ff, cU4, sp(ff))));          \
      f2 kV = pfma(mu_v, lV, pfma(NB, uv2, sp(-kpf) * cV4));                  \
      f2 aU = pfma(4.0f, y1u[9], kU);                                         \
      aU = pfma(8.0f, y2u[6], aU);                                            \
      aU = pfma(4.0f, cU4, aU);                                               \
      aU = pfma(-16.0f, du[5], aU);                                           \
      f2 aV = pfma(4.0f, y1v[9], kV);                                         \
      aV = pfma(8.0f, y2v[6], aV);                                            \
      aV = pfma(4.0f, cV4, aV);                                               \
      aV = pfma(-16.0f, dv[5], aV);                                           \
      f2 oUq = pfma(1.0f / 12.0f, aU, du[5]);                                 \
      f2 oVq = pfma(1.0f / 12.0f, aV, dv[5]);                                 \
      int yS = Y0 + t_ - 24;                                                  \
      *(f2*)(oU + (size_t)yS * 1024) = oUq;                                   \
      *(f2*)(oV + (size_t)yS * 1024) = oVq;                                   \
    }                                                                         \
    asm volatile("s_waitcnt lgkmcnt(0)" ::: "memory");                        \
    __builtin_amdgcn_s_barrier();                                             \
  }

    int t = 0;
    #pragma unroll 2
    for (; t < 6;  ++t) STEP(0, 0, 0, 0, t)
    #pragma unroll 2
    for (; t < 12; ++t) STEP(1, 0, 0, 0, t)
    #pragma unroll 2
    for (; t < 18; ++t) STEP(1, 1, 0, 0, t)
    #pragma unroll 2
    for (; t < 24; ++t) STEP(1, 1, 1, 0, t)
    #pragma unroll 4
    for (; t < STEPS; ++t) STEP(1, 1, 1, 1, t)
#undef STEP
}

extern "C" void kernel_launch(void* const* d_in, const int* in_sizes, int n_in,
                              void* d_out, int out_size, void* d_ws, size_t ws_size,
                              hipStream_t stream) {
    const float* h   = (const float*)d_in[0];
    const float* pCA = (const float*)d_in[1];
    const float* pCB = (const float*)d_in[2];
    const float* pNA = (const float*)d_in[3];
    const float* pNB = (const float*)d_in[4];
    const float* pf  = (const float*)d_in[5];
    const float* pk  = (const float*)d_in[6];
    float* outp = (float*)d_out;

    dim3 grid(1024 / HROWS, 1, 16);   // 16 strips x 16 batches = 256 blocks
    dim3 block(NT);
    rcnn_rk4_march<<<grid, block, 0, stream>>>(h, pCA, pCB, pNA, pNB, pf, pk, outp);
}